// Round 1
// baseline (4230.163 us; speedup 1.0000x reference)
//
#include <hip/hip_runtime.h>
#include <cstdint>

#define NBATCH 128
#define NT 512
#define NT1 513
#define NS 64
#define NACT 8
#define NU 512

__device__ __forceinline__ float sigf(float z) {
    return 1.0f / (1.0f + __expf(-z));
}
__device__ __forceinline__ float tanh_fast(float z) {
    // tanh(z) = 2*sigmoid(2z) - 1 ; safe at extremes (exp->inf or ->0)
    return 2.0f / (1.0f + __expf(-2.0f * z)) - 1.0f;
}
// round-to-nearest-even f32 -> bf16, result in TOP 16 bits
__device__ __forceinline__ uint32_t bf16_top(float f) {
    uint32_t u = __float_as_uint(f);
    u += 0x7FFFu + ((u >> 16) & 1u);
    return u & 0xFFFF0000u;
}
__device__ __forceinline__ float f_from_lo(uint32_t p) { return __uint_as_float(p << 16); }
__device__ __forceinline__ float f_from_hi(uint32_t p) { return __uint_as_float(p & 0xFFFF0000u); }

__device__ __forceinline__ void fma4(float4& acc, const float4 w, const float s) {
    acc.x = fmaf(w.x, s, acc.x);
    acc.y = fmaf(w.y, s, acc.y);
    acc.z = fmaf(w.z, s, acc.z);
    acc.w = fmaf(w.w, s, acc.w);
}

// ---------------------------------------------------------------------------
// Kernel A: feedforward gates for all (b,t): ci = tanh(x@W_ci + b_ci),
// og = sigmoid(x@W_og + b_og). One-hot action => single extra weight row.
// Stores packed bf16 (ci in low 16, og in high 16) into ws.
// Grid: 128 b * 17 t-tiles (TT=32), 512 threads (one per u).
// ---------------------------------------------------------------------------
__global__ __launch_bounds__(512) void ff_kernel(
    const float* __restrict__ states, const int* __restrict__ actions,
    const float* __restrict__ W_ci, const float* __restrict__ b_ci,
    const float* __restrict__ W_og, const float* __restrict__ b_og,
    uint32_t* __restrict__ ciog)
{
    __shared__ __align__(16) float sh_s[32][64];
    __shared__ int sh_a[32];
    const int tid = threadIdx.x;
    const int b = blockIdx.x / 17;
    const int t0 = (blockIdx.x % 17) * 32;
    const int tcnt = (t0 + 32 <= NT1) ? 32 : (NT1 - t0);

    const float* sp = states + ((size_t)b * NT1 + t0) * NS;
    for (int j = tid; j < tcnt * 16; j += 512) {
        const float4 v = *(const float4*)(sp + j * 4);
        *(float4*)&sh_s[j >> 4][(j & 15) * 4] = v;
    }
    for (int tt = tid; tt < tcnt; tt += 512) {
        const int t = t0 + tt;
        sh_a[tt] = (t < NT) ? actions[b * NT + t] : -1;
    }
    __syncthreads();

    const int u = tid;
    float accc[32], acco[32];
    const float bc = b_ci[u], bo = b_og[u];
    #pragma unroll
    for (int tt = 0; tt < 32; ++tt) { accc[tt] = bc; acco[tt] = bo; }

    for (int i = 0; i < NS; ++i) {
        const float wc = W_ci[(size_t)i * NU + u];
        const float wo = W_og[(size_t)i * NU + u];
        #pragma unroll
        for (int tt = 0; tt < 32; ++tt) {
            const float s = sh_s[tt][i];
            accc[tt] = fmaf(s, wc, accc[tt]);
            acco[tt] = fmaf(s, wo, acco[tt]);
        }
    }
    #pragma unroll
    for (int tt = 0; tt < 32; ++tt) {
        if (tt < tcnt) {
            float zc = accc[tt], zo = acco[tt];
            const int a = sh_a[tt];
            if (a >= 0) {
                zc += W_ci[(size_t)(NS + a) * NU + u];
                zo += W_og[(size_t)(NS + a) * NU + u];
            }
            const float ci = tanh_fast(zc);
            const float og = sigf(zo);
            ciog[((size_t)b * NT1 + t0 + tt) * NU + u] = bf16_top(og) | (bf16_top(ci) >> 16);
        }
    }
}

// ---------------------------------------------------------------------------
// Kernel B: sequential recurrence. One WG per 2 batch rows (64 WGs), 512 thr.
// Per step: phase1 = h @ W_ig partial matvec, threads tiled (kq in [0,4),
// uq in [0,128) handling a float4 of u). Phase2 = per-u gate math + state
// update + output reduction. c lives in regs, h in LDS. 2 barriers/step.
// PRE=true reads precomputed packed bf16 ci/og from ws; PRE=false recomputes.
// ---------------------------------------------------------------------------
template<bool PRE>
__global__ __launch_bounds__(512) void rec_kernel(
    const float* __restrict__ states, const int* __restrict__ actions,
    const float* __restrict__ W_ci, const float* __restrict__ b_ci,
    const float* __restrict__ W_ig, const float* __restrict__ b_ig,
    const float* __restrict__ W_og, const float* __restrict__ b_og,
    const float* __restrict__ W_lin, const float* __restrict__ b_lin,
    const uint32_t* __restrict__ ciog, float* __restrict__ out)
{
    __shared__ __align__(16) float h_lds[2][NU];
    __shared__ __align__(16) float part[4][2][NU];
    __shared__ float ysum[8][2];
    __shared__ float x_lds[2][NS];
    __shared__ int a_lds[2];

    const int tid = threadIdx.x;
    const int b0 = blockIdx.x * 2;
    const int uq = tid & 127;
    const int kq = tid >> 7;
    const int k0 = kq << 7;

    h_lds[0][tid] = 0.0f;
    h_lds[1][tid] = 0.0f;
    float c0 = 0.0f, c1 = 0.0f;
    const float wlin = W_lin[tid];
    const float big_ = b_ig[tid];
    const float blin = b_lin[0];
    float bc = 0.0f, bo = 0.0f;
    if (!PRE) { bc = b_ci[tid]; bo = b_og[tid]; }
    __syncthreads();

    for (int t = 0; t < NT1; ++t) {
        uint32_t pk0 = 0, pk1 = 0;
        if (PRE) {
            pk0 = ciog[((size_t)(b0 + 0) * NT1 + t) * NU + tid];
            pk1 = ciog[((size_t)(b0 + 1) * NT1 + t) * NU + tid];
        } else {
            if (tid < 128) {
                const int bb = tid >> 6, i = tid & 63;
                x_lds[bb][i] = states[((size_t)(b0 + bb) * NT1 + t) * NS + i];
            } else if (tid < 130) {
                const int bb = tid - 128;
                a_lds[bb] = (t < NT) ? actions[(b0 + bb) * NT + t] : -1;
            }
        }

        // ---- phase 1: partial matvec over k in [k0, k0+128) ----
        float4 a0 = make_float4(0.f, 0.f, 0.f, 0.f);
        float4 a1 = make_float4(0.f, 0.f, 0.f, 0.f);
        for (int kk = 0; kk < 128; kk += 4) {
            const int k = k0 + kk;
            const float4 h0v = *(const float4*)&h_lds[0][k];   // broadcast
            const float4 h1v = *(const float4*)&h_lds[1][k];   // broadcast
            const float* wr = W_ig + (size_t)k * NU + (uq << 2);
            const float4 w0 = *(const float4*)(wr);
            const float4 w1 = *(const float4*)(wr + NU);
            const float4 w2 = *(const float4*)(wr + 2 * NU);
            const float4 w3 = *(const float4*)(wr + 3 * NU);
            fma4(a0, w0, h0v.x); fma4(a1, w0, h1v.x);
            fma4(a0, w1, h0v.y); fma4(a1, w1, h1v.y);
            fma4(a0, w2, h0v.z); fma4(a1, w2, h1v.z);
            fma4(a0, w3, h0v.w); fma4(a1, w3, h1v.w);
        }
        *(float4*)&part[kq][0][uq << 2] = a0;
        *(float4*)&part[kq][1][uq << 2] = a1;
        __syncthreads();   // barrier 1

        // ---- phase 2: per-u state update (thread tid owns unit u=tid) ----
        float z0 = big_, z1 = big_;
        #pragma unroll
        for (int q = 0; q < 4; ++q) {
            z0 += part[q][0][tid];
            z1 += part[q][1][tid];
        }
        float ci0, og0, ci1, og1;
        if (PRE) {
            ci0 = f_from_lo(pk0); og0 = f_from_hi(pk0);
            ci1 = f_from_lo(pk1); og1 = f_from_hi(pk1);
        } else {
            float zc0 = bc, zo0 = bo, zc1 = bc, zo1 = bo;
            for (int i = 0; i < NS; ++i) {
                const float wc = W_ci[(size_t)i * NU + tid];
                const float wo = W_og[(size_t)i * NU + tid];
                const float s0v = x_lds[0][i];
                const float s1v = x_lds[1][i];
                zc0 = fmaf(s0v, wc, zc0); zo0 = fmaf(s0v, wo, zo0);
                zc1 = fmaf(s1v, wc, zc1); zo1 = fmaf(s1v, wo, zo1);
            }
            const int a0i = a_lds[0], a1i = a_lds[1];
            if (a0i >= 0) { zc0 += W_ci[(size_t)(NS + a0i) * NU + tid]; zo0 += W_og[(size_t)(NS + a0i) * NU + tid]; }
            if (a1i >= 0) { zc1 += W_ci[(size_t)(NS + a1i) * NU + tid]; zo1 += W_og[(size_t)(NS + a1i) * NU + tid]; }
            ci0 = tanh_fast(zc0); og0 = sigf(zo0);
            ci1 = tanh_fast(zc1); og1 = sigf(zo1);
        }
        const float ig0 = sigf(z0), ig1 = sigf(z1);
        c0 = fmaf(ci0, ig0, c0);
        c1 = fmaf(ci1, ig1, c1);
        const float h0 = c0 * og0, h1 = c1 * og1;
        h_lds[0][tid] = h0;
        h_lds[1][tid] = h1;

        // output projection: reduce h*W_lin across 512 threads
        float y0 = h0 * wlin, y1 = h1 * wlin;
        #pragma unroll
        for (int off = 32; off > 0; off >>= 1) {
            y0 += __shfl_xor(y0, off);
            y1 += __shfl_xor(y1, off);
        }
        if ((tid & 63) == 0) { ysum[tid >> 6][0] = y0; ysum[tid >> 6][1] = y1; }
        __syncthreads();   // barrier 2

        if (tid < 2) {
            float y = blin;
            #pragma unroll
            for (int w = 0; w < 8; ++w) y += ysum[w][tid];
            out[(size_t)(b0 + tid) * NT1 + t] = y;
        }
    }
}

extern "C" void kernel_launch(void* const* d_in, const int* in_sizes, int n_in,
                              void* d_out, int out_size, void* d_ws, size_t ws_size,
                              hipStream_t stream) {
    const float* states = (const float*)d_in[0];
    const int*   actions= (const int*)d_in[1];
    const float* W_ci = (const float*)d_in[2];
    const float* b_ci = (const float*)d_in[3];
    const float* W_ig = (const float*)d_in[4];
    const float* b_ig = (const float*)d_in[5];
    const float* W_og = (const float*)d_in[6];
    const float* b_og = (const float*)d_in[7];
    const float* W_lin= (const float*)d_in[8];
    const float* b_lin= (const float*)d_in[9];
    float* out = (float*)d_out;

    const size_t need = (size_t)NBATCH * NT1 * NU * sizeof(uint32_t);  // 134.5 MB
    if (ws_size >= need) {
        uint32_t* ciog = (uint32_t*)d_ws;
        ff_kernel<<<dim3(NBATCH * 17), dim3(512), 0, stream>>>(
            states, actions, W_ci, b_ci, W_og, b_og, ciog);
        rec_kernel<true><<<dim3(NBATCH / 2), dim3(512), 0, stream>>>(
            states, actions, W_ci, b_ci, W_ig, b_ig, W_og, b_og, W_lin, b_lin, ciog, out);
    } else {
        rec_kernel<false><<<dim3(NBATCH / 2), dim3(512), 0, stream>>>(
            states, actions, W_ci, b_ci, W_ig, b_ig, W_og, b_og, W_lin, b_lin, nullptr, out);
    }
}